// Round 3
// baseline (1445.227 us; speedup 1.0000x reference)
//
#include <hip/hip_runtime.h>
#include <cstdint>

typedef __bf16 bf16;
typedef __bf16 bf16x8 __attribute__((ext_vector_type(8)));
typedef float f32x4 __attribute__((ext_vector_type(4)));

#define NEG_SLOPE 0.2f
#define BN_EPS 1e-5f

// ---------------- async global->LDS (16B per lane, wave-uniform LDS base) ----------------
__device__ __forceinline__ void gld_lds16(const void* g, void* l) {
  auto gp = reinterpret_cast<const __attribute__((address_space(1))) unsigned int*>(
      reinterpret_cast<uintptr_t>(g));
  auto lp = reinterpret_cast<__attribute__((address_space(3))) unsigned int*>(
      reinterpret_cast<uintptr_t>(l));
  __builtin_amdgcn_global_load_lds(gp, lp, 16, 0, 0);
}

// ---------------- CSR build ----------------
__global__ void k_init_counts(int* counts, int N) {
  int i = blockIdx.x * 256 + threadIdx.x;
  if (i < N) counts[i] = 1;  // self-loop
}

__global__ void k_count(const int* __restrict__ ei, int* counts, int E) {
  int i = blockIdx.x * 256 + threadIdx.x;
  if (i < E) atomicAdd(&counts[ei[E + i]], 1);
}

__global__ void k_scan(const int* __restrict__ counts, int* __restrict__ row_start,
                       int* __restrict__ cursor, int N) {
  __shared__ int sdata[1024];
  __shared__ int s_carry;
  int t = threadIdx.x;
  if (t == 0) s_carry = 0;
  __syncthreads();
  for (int base = 0; base < N; base += 1024) {
    int i = base + t;
    int v = (i < N) ? counts[i] : 0;
    sdata[t] = v;
    __syncthreads();
    for (int ofs = 1; ofs < 1024; ofs <<= 1) {
      int x = (t >= ofs) ? sdata[t - ofs] : 0;
      __syncthreads();
      sdata[t] += x;
      __syncthreads();
    }
    int carry = s_carry;
    if (i < N) {
      int excl = carry + sdata[t] - v;
      row_start[i] = excl;
      cursor[i] = excl;
    }
    __syncthreads();
    if (t == 1023) s_carry = carry + sdata[1023];
    __syncthreads();
  }
  if (t == 0) row_start[N] = s_carry;
}

__global__ void k_fill(const int* __restrict__ ei, int* cursor, int* __restrict__ csr_src,
                       int E, int N) {
  int i = blockIdx.x * 256 + threadIdx.x;
  if (i < E) {
    int s = ei[i], d = ei[E + i];
    int p = atomicAdd(&cursor[d], 1);
    csr_src[p] = s;
  } else if (i < E + N) {
    int n = i - E;
    int p = atomicAdd(&cursor[n], 1);
    csr_src[p] = n;
  }
}

// ---------------- split fp32 -> (hi, lo) bf16 ----------------
__global__ void k_split(const float* __restrict__ src, bf16* __restrict__ hi,
                        bf16* __restrict__ lo, int n) {
  int i = blockIdx.x * 256 + threadIdx.x;
  if (i < n) {
    float v = src[i];
    bf16 h = (bf16)v;
    hi[i] = h;
    lo[i] = (bf16)(v - (float)h);
  }
}

// W [256k,256n] row-major -> Wt hi/lo [n][k] bf16
__global__ void k_transpose_w(const float* __restrict__ W, bf16* __restrict__ Wth,
                              bf16* __restrict__ Wtl) {
  int k = blockIdx.x, n = threadIdx.x;
  float v = W[k * 256 + n];
  bf16 h = (bf16)v;
  Wth[n * 256 + k] = h;
  Wtl[n * 256 + k] = (bf16)(v - (float)h);
}

// concat head weights [Wmu|Wlv|Wa|pad] -> transposed split [128][256] + bias_cat[128]
__global__ void k_build_head_w(const float* __restrict__ Wmu, const float* __restrict__ bmu,
                               const float* __restrict__ Wlv, const float* __restrict__ blv,
                               const float* __restrict__ Wa, const float* __restrict__ ba,
                               bf16* __restrict__ Whh, bf16* __restrict__ Whl,
                               float* __restrict__ bias_cat) {
  int k = blockIdx.x, n = threadIdx.x;  // k 0..255, n 0..127
  float v = 0.f;
  if (n < 32) v = Wmu[k * 32 + n];
  else if (n < 64) v = Wlv[k * 32 + (n - 32)];
  else if (n < 94) v = Wa[k * 30 + (n - 64)];
  bf16 h = (bf16)v;
  Whh[n * 256 + k] = h;
  Whl[n * 256 + k] = (bf16)(v - (float)h);
  if (k == 0) {
    float b = 0.f;
    if (n < 32) b = bmu[n];
    else if (n < 64) b = blv[n - 32];
    else if (n < 94) b = ba[n - 64];
    bias_cat[n] = b;
  }
}

// ---------------- split-precision bf16 MFMA GEMM ----------------
// C[M,ldc] = A[M,256] @ Bt^T + bias, A = Ah+Al, B = Bh+Bl (hi/lo bf16 planes), fp32 out.
__global__ __launch_bounds__(256) void k_gemm(
    const bf16* __restrict__ Ah, const bf16* __restrict__ Al,
    const bf16* __restrict__ Bh, const bf16* __restrict__ Bl,
    const float* __restrict__ bias, float* __restrict__ Cf, int M, int ldc) {
  __shared__ bf16 Ash[128 * 32];
  __shared__ bf16 Asl[128 * 32];
  __shared__ bf16 Bsh[128 * 32];
  __shared__ bf16 Bsl[128 * 32];
  const int t = threadIdx.x;
  const int wave = t >> 6, lane = t & 63;
  const int m0 = blockIdx.x * 128, n0 = blockIdx.y * 128;
  const int lrow = lane & 15, lq = lane >> 4;
  const int wm = (wave >> 1) * 64, wn = (wave & 1) * 64;

  f32x4 acc[4][4] = {};

  const int j0 = wave * 64 + lane, j1 = j0 + 256;
  const int ar0 = j0 >> 2, ar1 = j1 >> 2;
  const int ak0 = ((j0 & 3) ^ ((ar0 >> 1) & 3)) * 8;
  const int ak1 = ((j1 & 3) ^ ((ar1 >> 1) & 3)) * 8;
  const int gm0 = min(m0 + ar0, M - 1), gm1 = min(m0 + ar1, M - 1);
  const size_t oa0 = (size_t)gm0 * 256 + ak0, oa1 = (size_t)gm1 * 256 + ak1;
  const size_t ob0 = (size_t)(n0 + ar0) * 256 + ak0, ob1 = (size_t)(n0 + ar1) * 256 + ak1;
  const int l0 = wave * 512, l1 = 2048 + wave * 512;

  for (int k0 = 0; k0 < 256; k0 += 32) {
    __syncthreads();
    gld_lds16(Ah + oa0 + k0, Ash + l0);
    gld_lds16(Ah + oa1 + k0, Ash + l1);
    gld_lds16(Al + oa0 + k0, Asl + l0);
    gld_lds16(Al + oa1 + k0, Asl + l1);
    gld_lds16(Bh + ob0 + k0, Bsh + l0);
    gld_lds16(Bh + ob1 + k0, Bsh + l1);
    gld_lds16(Bl + ob0 + k0, Bsl + l0);
    gld_lds16(Bl + ob1 + k0, Bsl + l1);
    __syncthreads();
    bf16x8 afh[4], afl[4], bfh[4], bfl[4];
#pragma unroll
    for (int mi = 0; mi < 4; mi++) {
      int row = wm + mi * 16 + lrow;
      int off = row * 32 + ((lq ^ ((row >> 1) & 3)) << 3);
      afh[mi] = *(const bf16x8*)(Ash + off);
      afl[mi] = *(const bf16x8*)(Asl + off);
    }
#pragma unroll
    for (int ni = 0; ni < 4; ni++) {
      int row = wn + ni * 16 + lrow;
      int off = row * 32 + ((lq ^ ((row >> 1) & 3)) << 3);
      bfh[ni] = *(const bf16x8*)(Bsh + off);
      bfl[ni] = *(const bf16x8*)(Bsl + off);
    }
#pragma unroll
    for (int mi = 0; mi < 4; mi++)
#pragma unroll
      for (int ni = 0; ni < 4; ni++) {
        acc[mi][ni] = __builtin_amdgcn_mfma_f32_16x16x32_bf16(afl[mi], bfh[ni], acc[mi][ni], 0, 0, 0);
        acc[mi][ni] = __builtin_amdgcn_mfma_f32_16x16x32_bf16(afh[mi], bfl[ni], acc[mi][ni], 0, 0, 0);
        acc[mi][ni] = __builtin_amdgcn_mfma_f32_16x16x32_bf16(afh[mi], bfh[ni], acc[mi][ni], 0, 0, 0);
      }
  }

#pragma unroll
  for (int mi = 0; mi < 4; mi++) {
    const int mb = m0 + wm + mi * 16 + lq * 4;
#pragma unroll
    for (int ni = 0; ni < 4; ni++) {
      const int n = n0 + wn + ni * 16 + lrow;
#pragma unroll
      for (int r = 0; r < 4; r++) {
        int m = mb + r;
        if (m < M)
          Cf[(size_t)m * ldc + n] = acc[mi][ni][r] + (bias ? bias[n] : 0.f);
      }
    }
  }
}

// ---------------- per-node attention scores al_s/al_d [N,4] (fp32 h) ----------------
__global__ __launch_bounds__(256) void k_al(
    const float* __restrict__ h, const float* __restrict__ asrc, const float* __restrict__ adst,
    float* __restrict__ als, float* __restrict__ ald, int N) {
  const int t = threadIdx.x;
  const float as = asrc[t], ad = adst[t];
  const int head = t >> 6;
  int nend = min(blockIdx.x * 4 + 4, N);
  for (int n = blockIdx.x * 4; n < nend; ++n) {
    float hv = h[(size_t)n * 256 + t];
    float vs = hv * as, vd = hv * ad;
    for (int o = 32; o > 0; o >>= 1) {
      vs += __shfl_down(vs, o, 64);
      vd += __shfl_down(vd, o, 64);
    }
    if ((t & 63) == 0) { als[n * 4 + head] = vs; ald[n * 4 + head] = vd; }
  }
}

// ---------------- phase A: per-node softmax max + inv-sum (wave per node) ----------------
__global__ __launch_bounds__(256) void k_msum(
    const float* __restrict__ als, const float* __restrict__ ald,
    const int* __restrict__ row_start, const int* __restrict__ csr_src,
    float4* __restrict__ Mv, float4* __restrict__ Sinv, int N) {
  const int wave = threadIdx.x >> 6, lane = threadIdx.x & 63;
  const int n = blockIdx.x * 4 + wave;
  if (n >= N) return;
  const float4 ad = ((const float4*)ald)[n];
  const int beg = row_start[n], end = row_start[n + 1];
  float m0 = -__builtin_inff(), m1 = m0, m2 = m0, m3 = m0;
  for (int i = beg + lane; i < end; i += 64) {
    const float4 as = ((const float4*)als)[csr_src[i]];
    float e0 = as.x + ad.x; e0 = e0 > 0.f ? e0 : NEG_SLOPE * e0;
    float e1 = as.y + ad.y; e1 = e1 > 0.f ? e1 : NEG_SLOPE * e1;
    float e2 = as.z + ad.z; e2 = e2 > 0.f ? e2 : NEG_SLOPE * e2;
    float e3 = as.w + ad.w; e3 = e3 > 0.f ? e3 : NEG_SLOPE * e3;
    m0 = fmaxf(m0, e0); m1 = fmaxf(m1, e1); m2 = fmaxf(m2, e2); m3 = fmaxf(m3, e3);
  }
  for (int o = 32; o > 0; o >>= 1) {
    m0 = fmaxf(m0, __shfl_xor(m0, o, 64));
    m1 = fmaxf(m1, __shfl_xor(m1, o, 64));
    m2 = fmaxf(m2, __shfl_xor(m2, o, 64));
    m3 = fmaxf(m3, __shfl_xor(m3, o, 64));
  }
  float s0 = 0.f, s1 = 0.f, s2 = 0.f, s3 = 0.f;
  for (int i = beg + lane; i < end; i += 64) {
    const float4 as = ((const float4*)als)[csr_src[i]];
    float e0 = as.x + ad.x; e0 = e0 > 0.f ? e0 : NEG_SLOPE * e0;
    float e1 = as.y + ad.y; e1 = e1 > 0.f ? e1 : NEG_SLOPE * e1;
    float e2 = as.z + ad.z; e2 = e2 > 0.f ? e2 : NEG_SLOPE * e2;
    float e3 = as.w + ad.w; e3 = e3 > 0.f ? e3 : NEG_SLOPE * e3;
    s0 += __expf(e0 - m0); s1 += __expf(e1 - m1);
    s2 += __expf(e2 - m2); s3 += __expf(e3 - m3);
  }
  for (int o = 32; o > 0; o >>= 1) {
    s0 += __shfl_xor(s0, o, 64); s1 += __shfl_xor(s1, o, 64);
    s2 += __shfl_xor(s2, o, 64); s3 += __shfl_xor(s3, o, 64);
  }
  if (lane == 0) {
    Mv[n] = make_float4(m0, m1, m2, m3);
    Sinv[n] = make_float4(1.f / (s0 + 1e-16f), 1.f / (s1 + 1e-16f),
                          1.f / (s2 + 1e-16f), 1.f / (s3 + 1e-16f));
  }
}

// ---------------- phase B: weighted gather (wave per node, float4 per lane) ----------------
__global__ __launch_bounds__(256) void k_gather(
    const float* __restrict__ h, const float* __restrict__ als, const float* __restrict__ ald,
    const float4* __restrict__ Mv, const float4* __restrict__ Sinv,
    const int* __restrict__ row_start, const int* __restrict__ csr_src,
    const float* __restrict__ bias, float* __restrict__ out, int N) {
  const int wave = threadIdx.x >> 6, lane = threadIdx.x & 63;
  const int n = blockIdx.x * 4 + wave;
  if (n >= N) return;
  const int head = lane >> 4;
  const float4 ad4 = ((const float4*)ald)[n];
  const float4 m4 = Mv[n];
  const float4 is4 = Sinv[n];
  const float adh = head < 2 ? (head == 0 ? ad4.x : ad4.y) : (head == 2 ? ad4.z : ad4.w);
  const float mh = head < 2 ? (head == 0 ? m4.x : m4.y) : (head == 2 ? m4.z : m4.w);
  const float ish = head < 2 ? (head == 0 ? is4.x : is4.y) : (head == 2 ? is4.z : is4.w);
  const int beg = row_start[n], end = row_start[n + 1];
  float4 acc = {0.f, 0.f, 0.f, 0.f};
#pragma unroll 4
  for (int i = beg; i < end; ++i) {
    const int s = csr_src[i];
    const float4 a4 = ((const float4*)als)[s];
    float e = (head < 2 ? (head == 0 ? a4.x : a4.y) : (head == 2 ? a4.z : a4.w)) + adh;
    e = e > 0.f ? e : NEG_SLOPE * e;
    const float w = __expf(e - mh);
    const float4 hv = *(const float4*)(h + (size_t)s * 256 + lane * 4);
    acc.x += w * hv.x; acc.y += w * hv.y; acc.z += w * hv.z; acc.w += w * hv.w;
  }
  const float4 bv = *(const float4*)(bias + lane * 4);
  float4 o;
  o.x = acc.x * ish + bv.x; o.y = acc.y * ish + bv.y;
  o.z = acc.z * ish + bv.z; o.w = acc.w * ish + bv.w;
  *(float4*)(out + (size_t)n * 256 + lane * 4) = o;
}

// ---------------- batch norm ----------------
__global__ void k_zero(float* p, int n) {
  int i = blockIdx.x * 256 + threadIdx.x;
  if (i < n) p[i] = 0.f;
}

__global__ __launch_bounds__(256) void k_bn_stats(const float* __restrict__ x,
                                                  float* __restrict__ stats, int N) {
  const int t = threadIdx.x;
  int r0 = blockIdx.x * 128;
  int rend = min(r0 + 128, N);
  float s = 0.f, sq = 0.f;
  for (int r = r0; r < rend; ++r) {
    float v = x[(size_t)r * 256 + t];
    s += v; sq += v * v;
  }
  atomicAdd(&stats[t], s);
  atomicAdd(&stats[256 + t], sq);
}

// l<2: write split bf16 activation (hi/lo). l==2: encf[idx] = relu(bn) + encf[idx] (in-place add).
__global__ __launch_bounds__(256) void k_bn_apply(
    const float* __restrict__ x, const float* __restrict__ stats,
    const float* __restrict__ g, const float* __restrict__ be,
    bf16* __restrict__ act_hi, bf16* __restrict__ act_lo, float* __restrict__ encf,
    float invN, int total) {
  int idx = blockIdx.x * 256 + threadIdx.x;
  if (idx >= total) return;
  int c = idx & 255;
  float mu = stats[c] * invN;
  float var = stats[256 + c] * invN - mu * mu;
  float v = (x[idx] - mu) * rsqrtf(var + BN_EPS) * g[c] + be[c];
  v = fmaxf(v, 0.f);
  if (act_hi) {
    bf16 h = (bf16)v;
    act_hi[idx] = h;
    act_lo[idx] = (bf16)(v - (float)h);
  }
  if (encf) encf[idx] = v + encf[idx];
}

// ---------------- VAE finish: z, out = z@Wd, copy mu/lv/aux ----------------
__global__ __launch_bounds__(256) void k_finish(
    const float* __restrict__ HEAD, const float* __restrict__ eps,
    const float* __restrict__ Wd, const float* __restrict__ bd,
    float* __restrict__ o_out, float* __restrict__ o_mu, float* __restrict__ o_lv,
    float* __restrict__ o_aux, int N) {
  __shared__ float sWd[1024];
  __shared__ float sZ[8][33];
  const int t = threadIdx.x;
  for (int i = t; i < 1024; i += 256) sWd[i] = Wd[i];
  __syncthreads();
  const int r = t >> 5, j = t & 31;
  const int n = blockIdx.x * 8 + r;
  if (n < N) {
    const float* hp = HEAD + (size_t)n * 128;
    float mu = hp[j];
    float lv = hp[32 + j];
    float z = mu + eps[(size_t)n * 32 + j] * __expf(0.5f * lv);
    sZ[r][j] = z;
    o_mu[(size_t)n * 32 + j] = mu;
    o_lv[(size_t)n * 32 + j] = lv;
    if (j < 30) o_aux[(size_t)n * 30 + j] = hp[64 + j];
  }
  __syncthreads();
  if (n < N) {
    float o = bd[j];
#pragma unroll
    for (int k = 0; k < 32; ++k) o += sZ[r][k] * sWd[k * 32 + j];
    o_out[(size_t)n * 32 + j] = o;
  }
}

// ---------------- launcher ----------------
extern "C" void kernel_launch(void* const* d_in, const int* in_sizes, int n_in,
                              void* d_out, int out_size, void* d_ws, size_t ws_size,
                              hipStream_t stream) {
  const float* x   = (const float*)d_in[0];
  const int*   ei  = (const int*)d_in[1];
  const float* eps = (const float*)d_in[2];
  const float* Wg[3]   = {(const float*)d_in[3], (const float*)d_in[9],  (const float*)d_in[15]};
  const float* asrc[3] = {(const float*)d_in[4], (const float*)d_in[10], (const float*)d_in[16]};
  const float* adst[3] = {(const float*)d_in[5], (const float*)d_in[11], (const float*)d_in[17]};
  const float* bg[3]   = {(const float*)d_in[6], (const float*)d_in[12], (const float*)d_in[18]};
  const float* gam[3]  = {(const float*)d_in[7], (const float*)d_in[13], (const float*)d_in[19]};
  const float* bet[3]  = {(const float*)d_in[8], (const float*)d_in[14], (const float*)d_in[20]};
  const float* Wr  = (const float*)d_in[21];
  const float* br  = (const float*)d_in[22];
  const float* Wmu = (const float*)d_in[23];
  const float* bmu = (const float*)d_in[24];
  const float* Wlv = (const float*)d_in[25];
  const float* blv = (const float*)d_in[26];
  const float* Wd  = (const float*)d_in[27];
  const float* bd  = (const float*)d_in[28];
  const float* Wa  = (const float*)d_in[29];
  const float* ba  = (const float*)d_in[30];

  const int N = in_sizes[0] / 256;
  const int E = in_sizes[1] / 2;

  float* outp  = (float*)d_out;
  float* o_out = outp;
  float* o_mu  = outp + (size_t)N * 32;
  float* o_lv  = outp + (size_t)N * 64;
  float* o_aux = outp + (size_t)N * 96;
  float* o_enc = outp + (size_t)N * 96 + (size_t)N * 30;

  char* p = (char*)d_ws;
  auto carve = [&](size_t bytes) -> char* {
    char* r = p;
    p += (bytes + 255) & ~(size_t)255;
    return r;
  };
  int* counts    = (int*)carve((size_t)N * 4);
  int* row_start = (int*)carve(((size_t)N + 1) * 4);
  int* cursor    = (int*)carve((size_t)N * 4);
  int* csr_src   = (int*)carve((size_t)(E + N) * 4);
  bf16* Wth[4];
  bf16* Wtl[4];
  for (int i = 0; i < 4; ++i) {
    Wth[i] = (bf16*)carve(256 * 256 * 2);
    Wtl[i] = (bf16*)carve(256 * 256 * 2);
  }
  bf16* Whh = (bf16*)carve(128 * 256 * 2);
  bf16* Whl = (bf16*)carve(128 * 256 * 2);
  float* bias_cat = (float*)carve(128 * 4);
  bf16* Ahi = (bf16*)carve((size_t)N * 256 * 2);
  bf16* Alo = (bf16*)carve((size_t)N * 256 * 2);
  float* H   = (float*)carve((size_t)N * 256 * 4);  // h buffer; reused as HEAD [N,128] at end
  float* AGG = (float*)carve((size_t)N * 256 * 4);
  float* als = (float*)carve((size_t)N * 4 * 4);
  float* ald = (float*)carve((size_t)N * 4 * 4);
  float4* Mv   = (float4*)carve((size_t)N * 16);
  float4* Sinv = (float4*)carve((size_t)N * 16);
  float* stats = (float*)carve(512 * 4);

  dim3 b256(256);

  // CSR by dst (self-loops included as count init = 1)
  k_init_counts<<<(N + 255) / 256, b256, 0, stream>>>(counts, N);
  k_count<<<(E + 255) / 256, b256, 0, stream>>>(ei, counts, E);
  k_scan<<<1, 1024, 0, stream>>>(counts, row_start, cursor, N);
  k_fill<<<(E + N + 255) / 256, b256, 0, stream>>>(ei, cursor, csr_src, E, N);

  // conversions
  k_split<<<((size_t)N * 256 + 255) / 256, b256, 0, stream>>>(x, Ahi, Alo, N * 256);
  k_transpose_w<<<256, b256, 0, stream>>>(Wr, Wth[0], Wtl[0]);
  for (int l = 0; l < 3; ++l)
    k_transpose_w<<<256, b256, 0, stream>>>(Wg[l], Wth[l + 1], Wtl[l + 1]);
  k_build_head_w<<<256, dim3(128), 0, stream>>>(Wmu, bmu, Wlv, blv, Wa, ba, Whh, Whl, bias_cat);

  dim3 ggrid((N + 127) / 128, 2);
  // residual = x @ Wr + br -> o_enc (bn3 adds relu(bn) in-place later)
  k_gemm<<<ggrid, b256, 0, stream>>>(Ahi, Alo, Wth[0], Wtl[0], br, o_enc, N, 256);

  const float invN = 1.0f / (float)N;
  const int nwb = (N + 3) / 4;
  for (int l = 0; l < 3; ++l) {
    k_gemm<<<ggrid, b256, 0, stream>>>(Ahi, Alo, Wth[l + 1], Wtl[l + 1], nullptr, H, N, 256);
    k_al<<<nwb, b256, 0, stream>>>(H, asrc[l], adst[l], als, ald, N);
    k_zero<<<2, b256, 0, stream>>>(stats, 512);
    k_msum<<<nwb, b256, 0, stream>>>(als, ald, row_start, csr_src, Mv, Sinv, N);
    k_gather<<<nwb, b256, 0, stream>>>(H, als, ald, Mv, Sinv, row_start, csr_src, bg[l], AGG, N);
    k_bn_stats<<<(N + 127) / 128, b256, 0, stream>>>(AGG, stats, N);
    if (l < 2)
      k_bn_apply<<<((size_t)N * 256 + 255) / 256, b256, 0, stream>>>(
          AGG, stats, gam[l], bet[l], Ahi, Alo, nullptr, invN, N * 256);
    else
      k_bn_apply<<<((size_t)N * 256 + 255) / 256, b256, 0, stream>>>(
          AGG, stats, gam[l], bet[l], nullptr, nullptr, o_enc, invN, N * 256);
  }

  // enc -> split bf16 for head GEMM
  k_split<<<((size_t)N * 256 + 255) / 256, b256, 0, stream>>>(o_enc, Ahi, Alo, N * 256);
  // HEAD[N,128] = enc @ [Wmu|Wlv|Wa] + bias_cat  (reuses H buffer)
  dim3 hgrid((N + 127) / 128, 1);
  k_gemm<<<hgrid, b256, 0, stream>>>(Ahi, Alo, Whh, Whl, bias_cat, H, N, 128);
  k_finish<<<(N + 7) / 8, b256, 0, stream>>>(H, eps, Wd, bd, o_out, o_mu, o_lv, o_aux, N);
}

// Round 4
// 1074.243 us; speedup vs baseline: 1.3453x; 1.3453x over previous
//
#include <hip/hip_runtime.h>
#include <cstdint>

typedef __bf16 bf16;
typedef __bf16 bf16x8 __attribute__((ext_vector_type(8)));
typedef float f32x4 __attribute__((ext_vector_type(4)));
typedef _Float16 fp16;
typedef _Float16 half8 __attribute__((ext_vector_type(8)));

#define NEG_SLOPE 0.2f
#define BN_EPS 1e-5f

// ---------------- async global->LDS (16B per lane, wave-uniform LDS base) ----------------
__device__ __forceinline__ void gld_lds16(const void* g, void* l) {
  auto gp = reinterpret_cast<const __attribute__((address_space(1))) unsigned int*>(
      reinterpret_cast<uintptr_t>(g));
  auto lp = reinterpret_cast<__attribute__((address_space(3))) unsigned int*>(
      reinterpret_cast<uintptr_t>(l));
  __builtin_amdgcn_global_load_lds(gp, lp, 16, 0, 0);
}

// ---------------- CSR build ----------------
__global__ void k_init_counts(int* counts, int N) {
  int i = blockIdx.x * 256 + threadIdx.x;
  if (i < N) counts[i] = 1;  // self-loop
}

__global__ void k_count(const int* __restrict__ ei, int* counts, int E) {
  int i = blockIdx.x * 256 + threadIdx.x;
  if (i < E) atomicAdd(&counts[ei[E + i]], 1);
}

__global__ void k_scan(const int* __restrict__ counts, int* __restrict__ row_start,
                       int* __restrict__ cursor, int N) {
  __shared__ int sdata[1024];
  __shared__ int s_carry;
  int t = threadIdx.x;
  if (t == 0) s_carry = 0;
  __syncthreads();
  for (int base = 0; base < N; base += 1024) {
    int i = base + t;
    int v = (i < N) ? counts[i] : 0;
    sdata[t] = v;
    __syncthreads();
    for (int ofs = 1; ofs < 1024; ofs <<= 1) {
      int x = (t >= ofs) ? sdata[t - ofs] : 0;
      __syncthreads();
      sdata[t] += x;
      __syncthreads();
    }
    int carry = s_carry;
    if (i < N) {
      int excl = carry + sdata[t] - v;
      row_start[i] = excl;
      cursor[i] = excl;
    }
    __syncthreads();
    if (t == 1023) s_carry = carry + sdata[1023];
    __syncthreads();
  }
  if (t == 0) row_start[N] = s_carry;
}

__global__ void k_fill(const int* __restrict__ ei, int* cursor, int* __restrict__ csr_src,
                       int E, int N) {
  int i = blockIdx.x * 256 + threadIdx.x;
  if (i < E) {
    int s = ei[i], d = ei[E + i];
    int p = atomicAdd(&cursor[d], 1);
    csr_src[p] = s;
  } else if (i < E + N) {
    int n = i - E;
    int p = atomicAdd(&cursor[n], 1);
    csr_src[p] = n;
  }
}

// ---------------- split fp32 -> (hi, lo) bf16 ----------------
__global__ void k_split(const float* __restrict__ src, bf16* __restrict__ hi,
                        bf16* __restrict__ lo, int n) {
  int i = blockIdx.x * 256 + threadIdx.x;
  if (i < n) {
    float v = src[i];
    bf16 h = (bf16)v;
    hi[i] = h;
    lo[i] = (bf16)(v - (float)h);
  }
}

// W [256k,256n] row-major -> Wt hi/lo [n][k] bf16
__global__ void k_transpose_w(const float* __restrict__ W, bf16* __restrict__ Wth,
                              bf16* __restrict__ Wtl) {
  int k = blockIdx.x, n = threadIdx.x;
  float v = W[k * 256 + n];
  bf16 h = (bf16)v;
  Wth[n * 256 + k] = h;
  Wtl[n * 256 + k] = (bf16)(v - (float)h);
}

// concat head weights [Wmu|Wlv|Wa|pad] -> transposed split [128][256] + bias_cat[128]
__global__ void k_build_head_w(const float* __restrict__ Wmu, const float* __restrict__ bmu,
                               const float* __restrict__ Wlv, const float* __restrict__ blv,
                               const float* __restrict__ Wa, const float* __restrict__ ba,
                               bf16* __restrict__ Whh, bf16* __restrict__ Whl,
                               float* __restrict__ bias_cat) {
  int k = blockIdx.x, n = threadIdx.x;  // k 0..255, n 0..127
  float v = 0.f;
  if (n < 32) v = Wmu[k * 32 + n];
  else if (n < 64) v = Wlv[k * 32 + (n - 32)];
  else if (n < 94) v = Wa[k * 30 + (n - 64)];
  bf16 h = (bf16)v;
  Whh[n * 256 + k] = h;
  Whl[n * 256 + k] = (bf16)(v - (float)h);
  if (k == 0) {
    float b = 0.f;
    if (n < 32) b = bmu[n];
    else if (n < 64) b = blv[n - 32];
    else if (n < 94) b = ba[n - 64];
    bias_cat[n] = b;
  }
}

// ---------------- split-precision bf16 MFMA GEMM ----------------
// C[M,ldc] = A[M,256] @ Bt^T + bias. Output: fp32 Cf (with bias) OR fp16 C16 (no bias).
__global__ __launch_bounds__(256) void k_gemm(
    const bf16* __restrict__ Ah, const bf16* __restrict__ Al,
    const bf16* __restrict__ Bh, const bf16* __restrict__ Bl,
    const float* __restrict__ bias, float* __restrict__ Cf, fp16* __restrict__ C16,
    int M, int ldc) {
  __shared__ bf16 Ash[128 * 32];
  __shared__ bf16 Asl[128 * 32];
  __shared__ bf16 Bsh[128 * 32];
  __shared__ bf16 Bsl[128 * 32];
  const int t = threadIdx.x;
  const int wave = t >> 6, lane = t & 63;
  const int m0 = blockIdx.x * 128, n0 = blockIdx.y * 128;
  const int lrow = lane & 15, lq = lane >> 4;
  const int wm = (wave >> 1) * 64, wn = (wave & 1) * 64;

  f32x4 acc[4][4] = {};

  const int j0 = wave * 64 + lane, j1 = j0 + 256;
  const int ar0 = j0 >> 2, ar1 = j1 >> 2;
  const int ak0 = ((j0 & 3) ^ ((ar0 >> 1) & 3)) * 8;
  const int ak1 = ((j1 & 3) ^ ((ar1 >> 1) & 3)) * 8;
  const int gm0 = min(m0 + ar0, M - 1), gm1 = min(m0 + ar1, M - 1);
  const size_t oa0 = (size_t)gm0 * 256 + ak0, oa1 = (size_t)gm1 * 256 + ak1;
  const size_t ob0 = (size_t)(n0 + ar0) * 256 + ak0, ob1 = (size_t)(n0 + ar1) * 256 + ak1;
  const int l0 = wave * 512, l1 = 2048 + wave * 512;

  for (int k0 = 0; k0 < 256; k0 += 32) {
    __syncthreads();
    gld_lds16(Ah + oa0 + k0, Ash + l0);
    gld_lds16(Ah + oa1 + k0, Ash + l1);
    gld_lds16(Al + oa0 + k0, Asl + l0);
    gld_lds16(Al + oa1 + k0, Asl + l1);
    gld_lds16(Bh + ob0 + k0, Bsh + l0);
    gld_lds16(Bh + ob1 + k0, Bsh + l1);
    gld_lds16(Bl + ob0 + k0, Bsl + l0);
    gld_lds16(Bl + ob1 + k0, Bsl + l1);
    __syncthreads();
    bf16x8 afh[4], afl[4], bfh[4], bfl[4];
#pragma unroll
    for (int mi = 0; mi < 4; mi++) {
      int row = wm + mi * 16 + lrow;
      int off = row * 32 + ((lq ^ ((row >> 1) & 3)) << 3);
      afh[mi] = *(const bf16x8*)(Ash + off);
      afl[mi] = *(const bf16x8*)(Asl + off);
    }
#pragma unroll
    for (int ni = 0; ni < 4; ni++) {
      int row = wn + ni * 16 + lrow;
      int off = row * 32 + ((lq ^ ((row >> 1) & 3)) << 3);
      bfh[ni] = *(const bf16x8*)(Bsh + off);
      bfl[ni] = *(const bf16x8*)(Bsl + off);
    }
#pragma unroll
    for (int mi = 0; mi < 4; mi++)
#pragma unroll
      for (int ni = 0; ni < 4; ni++) {
        acc[mi][ni] = __builtin_amdgcn_mfma_f32_16x16x32_bf16(afl[mi], bfh[ni], acc[mi][ni], 0, 0, 0);
        acc[mi][ni] = __builtin_amdgcn_mfma_f32_16x16x32_bf16(afh[mi], bfl[ni], acc[mi][ni], 0, 0, 0);
        acc[mi][ni] = __builtin_amdgcn_mfma_f32_16x16x32_bf16(afh[mi], bfh[ni], acc[mi][ni], 0, 0, 0);
      }
  }

#pragma unroll
  for (int mi = 0; mi < 4; mi++) {
    const int mb = m0 + wm + mi * 16 + lq * 4;
#pragma unroll
    for (int ni = 0; ni < 4; ni++) {
      const int n = n0 + wn + ni * 16 + lrow;
#pragma unroll
      for (int r = 0; r < 4; r++) {
        int m = mb + r;
        if (m < M) {
          if (C16) C16[(size_t)m * ldc + n] = (fp16)acc[mi][ni][r];
          else     Cf[(size_t)m * ldc + n] = acc[mi][ni][r] + (bias ? bias[n] : 0.f);
        }
      }
    }
  }
}

// ---------------- per-node attention scores al_s/al_d [N,4] (fp16 h) ----------------
__global__ __launch_bounds__(256) void k_al(
    const fp16* __restrict__ h, const float* __restrict__ asrc, const float* __restrict__ adst,
    float* __restrict__ als, float* __restrict__ ald, int N) {
  const int t = threadIdx.x;
  const float as = asrc[t], ad = adst[t];
  const int head = t >> 6;
  int nend = min(blockIdx.x * 4 + 4, N);
  for (int n = blockIdx.x * 4; n < nend; ++n) {
    float hv = (float)h[(size_t)n * 256 + t];
    float vs = hv * as, vd = hv * ad;
    for (int o = 32; o > 0; o >>= 1) {
      vs += __shfl_down(vs, o, 64);
      vd += __shfl_down(vd, o, 64);
    }
    if ((t & 63) == 0) { als[n * 4 + head] = vs; ald[n * 4 + head] = vd; }
  }
}

// -------- online softmax + weighted gather: 2 nodes/wave, lane owns 8 fp16 channels ------
__global__ __launch_bounds__(256) void k_gather(
    const fp16* __restrict__ h16, const float* __restrict__ als, const float* __restrict__ ald,
    const int* __restrict__ row_start, const int* __restrict__ csr_src,
    const float* __restrict__ bias, float* __restrict__ out, int N) {
  const int wave = threadIdx.x >> 6, lane = threadIdx.x & 63;
  const int half = lane >> 5, l32 = lane & 31;
  const int n = blockIdx.x * 8 + wave * 2 + half;
  if (n >= N) return;
  const int head = l32 >> 3;
  const int c0 = l32 * 8;
  const float adh = ald[n * 4 + head];
  const int beg = row_start[n], end = row_start[n + 1];
  float m = -__builtin_inff(), s = 0.f;
  float acc[8] = {0.f, 0.f, 0.f, 0.f, 0.f, 0.f, 0.f, 0.f};
#pragma unroll 4
  for (int i = beg; i < end; ++i) {
    const int sidx = csr_src[i];
    float e = als[sidx * 4 + head] + adh;
    e = e > 0.f ? e : NEG_SLOPE * e;
    const float mnew = fmaxf(m, e);
    const float sc = __expf(m - mnew);   // first iter: exp(-inf)=0
    const float w = __expf(e - mnew);
    m = mnew;
    s = s * sc + w;
    const half8 hv = *(const half8*)(h16 + (size_t)sidx * 256 + c0);
#pragma unroll
    for (int k = 0; k < 8; ++k) acc[k] = acc[k] * sc + w * (float)hv[k];
  }
  const float inv = 1.f / (s + 1e-16f);
  float4 o1, o2;
  const float4 b1 = *(const float4*)(bias + c0);
  const float4 b2 = *(const float4*)(bias + c0 + 4);
  o1.x = acc[0] * inv + b1.x; o1.y = acc[1] * inv + b1.y;
  o1.z = acc[2] * inv + b1.z; o1.w = acc[3] * inv + b1.w;
  o2.x = acc[4] * inv + b2.x; o2.y = acc[5] * inv + b2.y;
  o2.z = acc[6] * inv + b2.z; o2.w = acc[7] * inv + b2.w;
  *(float4*)(out + (size_t)n * 256 + c0) = o1;
  *(float4*)(out + (size_t)n * 256 + c0 + 4) = o2;
}

// ---------------- batch norm ----------------
__global__ void k_zero(float* p, int n) {
  int i = blockIdx.x * 256 + threadIdx.x;
  if (i < n) p[i] = 0.f;
}

__global__ __launch_bounds__(256) void k_bn_stats(const float* __restrict__ x,
                                                  float* __restrict__ stats, int N) {
  const int t = threadIdx.x;
  int r0 = blockIdx.x * 128;
  int rend = min(r0 + 128, N);
  float s = 0.f, sq = 0.f;
  for (int r = r0; r < rend; ++r) {
    float v = x[(size_t)r * 256 + t];
    s += v; sq += v * v;
  }
  atomicAdd(&stats[t], s);
  atomicAdd(&stats[256 + t], sq);
}

// l<2: write split bf16 activation (hi/lo). l==2: encf[idx] = relu(bn) + encf[idx] (in-place add).
__global__ __launch_bounds__(256) void k_bn_apply(
    const float* __restrict__ x, const float* __restrict__ stats,
    const float* __restrict__ g, const float* __restrict__ be,
    bf16* __restrict__ act_hi, bf16* __restrict__ act_lo, float* __restrict__ encf,
    float invN, int total) {
  int idx = blockIdx.x * 256 + threadIdx.x;
  if (idx >= total) return;
  int c = idx & 255;
  float mu = stats[c] * invN;
  float var = stats[256 + c] * invN - mu * mu;
  float v = (x[idx] - mu) * rsqrtf(var + BN_EPS) * g[c] + be[c];
  v = fmaxf(v, 0.f);
  if (act_hi) {
    bf16 h = (bf16)v;
    act_hi[idx] = h;
    act_lo[idx] = (bf16)(v - (float)h);
  }
  if (encf) encf[idx] = v + encf[idx];
}

// ---------------- VAE finish: z, out = z@Wd, copy mu/lv/aux ----------------
__global__ __launch_bounds__(256) void k_finish(
    const float* __restrict__ HEAD, const float* __restrict__ eps,
    const float* __restrict__ Wd, const float* __restrict__ bd,
    float* __restrict__ o_out, float* __restrict__ o_mu, float* __restrict__ o_lv,
    float* __restrict__ o_aux, int N) {
  __shared__ float sWd[1024];
  __shared__ float sZ[8][33];
  const int t = threadIdx.x;
  for (int i = t; i < 1024; i += 256) sWd[i] = Wd[i];
  __syncthreads();
  const int r = t >> 5, j = t & 31;
  const int n = blockIdx.x * 8 + r;
  if (n < N) {
    const float* hp = HEAD + (size_t)n * 128;
    float mu = hp[j];
    float lv = hp[32 + j];
    float z = mu + eps[(size_t)n * 32 + j] * __expf(0.5f * lv);
    sZ[r][j] = z;
    o_mu[(size_t)n * 32 + j] = mu;
    o_lv[(size_t)n * 32 + j] = lv;
    if (j < 30) o_aux[(size_t)n * 30 + j] = hp[64 + j];
  }
  __syncthreads();
  if (n < N) {
    float o = bd[j];
#pragma unroll
    for (int k = 0; k < 32; ++k) o += sZ[r][k] * sWd[k * 32 + j];
    o_out[(size_t)n * 32 + j] = o;
  }
}

// ---------------- launcher ----------------
extern "C" void kernel_launch(void* const* d_in, const int* in_sizes, int n_in,
                              void* d_out, int out_size, void* d_ws, size_t ws_size,
                              hipStream_t stream) {
  const float* x   = (const float*)d_in[0];
  const int*   ei  = (const int*)d_in[1];
  const float* eps = (const float*)d_in[2];
  const float* Wg[3]   = {(const float*)d_in[3], (const float*)d_in[9],  (const float*)d_in[15]};
  const float* asrc[3] = {(const float*)d_in[4], (const float*)d_in[10], (const float*)d_in[16]};
  const float* adst[3] = {(const float*)d_in[5], (const float*)d_in[11], (const float*)d_in[17]};
  const float* bg[3]   = {(const float*)d_in[6], (const float*)d_in[12], (const float*)d_in[18]};
  const float* gam[3]  = {(const float*)d_in[7], (const float*)d_in[13], (const float*)d_in[19]};
  const float* bet[3]  = {(const float*)d_in[8], (const float*)d_in[14], (const float*)d_in[20]};
  const float* Wr  = (const float*)d_in[21];
  const float* br  = (const float*)d_in[22];
  const float* Wmu = (const float*)d_in[23];
  const float* bmu = (const float*)d_in[24];
  const float* Wlv = (const float*)d_in[25];
  const float* blv = (const float*)d_in[26];
  const float* Wd  = (const float*)d_in[27];
  const float* bd  = (const float*)d_in[28];
  const float* Wa  = (const float*)d_in[29];
  const float* ba  = (const float*)d_in[30];

  const int N = in_sizes[0] / 256;
  const int E = in_sizes[1] / 2;

  float* outp  = (float*)d_out;
  float* o_out = outp;
  float* o_mu  = outp + (size_t)N * 32;
  float* o_lv  = outp + (size_t)N * 64;
  float* o_aux = outp + (size_t)N * 96;
  float* o_enc = outp + (size_t)N * 96 + (size_t)N * 30;

  char* p = (char*)d_ws;
  auto carve = [&](size_t bytes) -> char* {
    char* r = p;
    p += (bytes + 255) & ~(size_t)255;
    return r;
  };
  int* counts    = (int*)carve((size_t)N * 4);
  int* row_start = (int*)carve(((size_t)N + 1) * 4);
  int* cursor    = (int*)carve((size_t)N * 4);
  int* csr_src   = (int*)carve((size_t)(E + N) * 4);
  bf16* Wth[4];
  bf16* Wtl[4];
  for (int i = 0; i < 4; ++i) {
    Wth[i] = (bf16*)carve(256 * 256 * 2);
    Wtl[i] = (bf16*)carve(256 * 256 * 2);
  }
  bf16* Whh = (bf16*)carve(128 * 256 * 2);
  bf16* Whl = (bf16*)carve(128 * 256 * 2);
  float* bias_cat = (float*)carve(128 * 4);
  bf16* Ahi = (bf16*)carve((size_t)N * 256 * 2);
  bf16* Alo = (bf16*)carve((size_t)N * 256 * 2);
  fp16* H16 = (fp16*)carve((size_t)N * 256 * 2);   // h in fp16 for scores+gather
  float* FHEAD = (float*)carve((size_t)N * 128 * 4);  // head GEMM out
  float* AGG = (float*)carve((size_t)N * 256 * 4);
  float* als = (float*)carve((size_t)N * 4 * 4);
  float* ald = (float*)carve((size_t)N * 4 * 4);
  float* stats = (float*)carve(512 * 4);

  dim3 b256(256);

  // CSR by dst (self-loops included as count init = 1)
  k_init_counts<<<(N + 255) / 256, b256, 0, stream>>>(counts, N);
  k_count<<<(E + 255) / 256, b256, 0, stream>>>(ei, counts, E);
  k_scan<<<1, 1024, 0, stream>>>(counts, row_start, cursor, N);
  k_fill<<<(E + N + 255) / 256, b256, 0, stream>>>(ei, cursor, csr_src, E, N);

  // conversions
  k_split<<<((size_t)N * 256 + 255) / 256, b256, 0, stream>>>(x, Ahi, Alo, N * 256);
  k_transpose_w<<<256, b256, 0, stream>>>(Wr, Wth[0], Wtl[0]);
  for (int l = 0; l < 3; ++l)
    k_transpose_w<<<256, b256, 0, stream>>>(Wg[l], Wth[l + 1], Wtl[l + 1]);
  k_build_head_w<<<256, dim3(128), 0, stream>>>(Wmu, bmu, Wlv, blv, Wa, ba, Whh, Whl, bias_cat);

  dim3 ggrid((N + 127) / 128, 2);
  // residual = x @ Wr + br -> o_enc (bn3 adds relu(bn) in-place later)
  k_gemm<<<ggrid, b256, 0, stream>>>(Ahi, Alo, Wth[0], Wtl[0], br, o_enc, nullptr, N, 256);

  const float invN = 1.0f / (float)N;
  for (int l = 0; l < 3; ++l) {
    k_gemm<<<ggrid, b256, 0, stream>>>(Ahi, Alo, Wth[l + 1], Wtl[l + 1], nullptr, nullptr, H16, N, 256);
    k_al<<<(N + 3) / 4, b256, 0, stream>>>(H16, asrc[l], adst[l], als, ald, N);
    k_zero<<<2, b256, 0, stream>>>(stats, 512);
    k_gather<<<(N + 7) / 8, b256, 0, stream>>>(H16, als, ald, row_start, csr_src, bg[l], AGG, N);
    k_bn_stats<<<(N + 127) / 128, b256, 0, stream>>>(AGG, stats, N);
    if (l < 2)
      k_bn_apply<<<((size_t)N * 256 + 255) / 256, b256, 0, stream>>>(
          AGG, stats, gam[l], bet[l], Ahi, Alo, nullptr, invN, N * 256);
    else
      k_bn_apply<<<((size_t)N * 256 + 255) / 256, b256, 0, stream>>>(
          AGG, stats, gam[l], bet[l], nullptr, nullptr, o_enc, invN, N * 256);
  }

  // enc -> split bf16 for head GEMM
  k_split<<<((size_t)N * 256 + 255) / 256, b256, 0, stream>>>(o_enc, Ahi, Alo, N * 256);
  // HEAD[N,128] = enc @ [Wmu|Wlv|Wa] + bias_cat
  dim3 hgrid((N + 127) / 128, 1);
  k_gemm<<<hgrid, b256, 0, stream>>>(Ahi, Alo, Whh, Whl, bias_cat, FHEAD, nullptr, N, 128);
  k_finish<<<(N + 7) / 8, b256, 0, stream>>>(FHEAD, eps, Wd, bd, o_out, o_mu, o_lv, o_aux, N);
}

// Round 5
// 991.082 us; speedup vs baseline: 1.4582x; 1.0839x over previous
//
#include <hip/hip_runtime.h>
#include <cstdint>

typedef __bf16 bf16;
typedef __bf16 bf16x8 __attribute__((ext_vector_type(8)));
typedef float f32x4 __attribute__((ext_vector_type(4)));
typedef _Float16 fp16;
typedef _Float16 half8 __attribute__((ext_vector_type(8)));

#define NEG_SLOPE 0.2f
#define BN_EPS 1e-5f

// ---------------- async global->LDS (16B per lane, wave-uniform LDS base) ----------------
__device__ __forceinline__ void gld_lds16(const void* g, void* l) {
  auto gp = reinterpret_cast<const __attribute__((address_space(1))) unsigned int*>(
      reinterpret_cast<uintptr_t>(g));
  auto lp = reinterpret_cast<__attribute__((address_space(3))) unsigned int*>(
      reinterpret_cast<uintptr_t>(l));
  __builtin_amdgcn_global_load_lds(gp, lp, 16, 0, 0);
}

// ---------------- CSR build ----------------
__global__ void k_init_counts(int* counts, int N) {
  int i = blockIdx.x * 256 + threadIdx.x;
  if (i < N) counts[i] = 1;  // self-loop
}

__global__ void k_count(const int* __restrict__ ei, int* counts, int E) {
  int i = blockIdx.x * 256 + threadIdx.x;
  if (i < E) atomicAdd(&counts[ei[E + i]], 1);
}

// phase 1: each block scans 1024 counts; writes local exclusive prefix into row_start,
// block total into bsums[blockIdx]
__global__ __launch_bounds__(256) void k_scan1(const int* __restrict__ counts,
                                               int* __restrict__ row_start,
                                               int* __restrict__ bsums, int N) {
  __shared__ int s[256];
  const int t = threadIdx.x;
  const int idx = blockIdx.x * 1024 + t * 4;
  int a0 = (idx + 0 < N) ? counts[idx + 0] : 0;
  int a1 = (idx + 1 < N) ? counts[idx + 1] : 0;
  int a2 = (idx + 2 < N) ? counts[idx + 2] : 0;
  int a3 = (idx + 3 < N) ? counts[idx + 3] : 0;
  const int mysum = a0 + a1 + a2 + a3;
  s[t] = mysum;
  __syncthreads();
  for (int ofs = 1; ofs < 256; ofs <<= 1) {
    int v = (t >= ofs) ? s[t - ofs] : 0;
    __syncthreads();
    s[t] += v;
    __syncthreads();
  }
  int excl = s[t] - mysum;
  if (idx + 0 < N) row_start[idx + 0] = excl;
  if (idx + 1 < N) row_start[idx + 1] = excl + a0;
  if (idx + 2 < N) row_start[idx + 2] = excl + a0 + a1;
  if (idx + 3 < N) row_start[idx + 3] = excl + a0 + a1 + a2;
  if (t == 255) bsums[blockIdx.x] = s[255];
}

// phase 2: serial exclusive scan of block sums (nb ~ 49); writes row_start[N] = total
__global__ void k_scan2(int* __restrict__ bsums, int* __restrict__ row_start, int nb, int N) {
  if (threadIdx.x == 0 && blockIdx.x == 0) {
    int run = 0;
    for (int i = 0; i < nb; ++i) {
      int v = bsums[i];
      bsums[i] = run;
      run += v;
    }
    row_start[N] = run;
  }
}

// phase 3: add block offsets; mirror into cursor
__global__ void k_scan3(int* __restrict__ row_start, int* __restrict__ cursor,
                        const int* __restrict__ bsums, int N) {
  int i = blockIdx.x * 256 + threadIdx.x;
  if (i < N) {
    int v = row_start[i] + bsums[i >> 10];
    row_start[i] = v;
    cursor[i] = v;
  }
}

__global__ void k_fill(const int* __restrict__ ei, int* cursor, int* __restrict__ csr_src,
                       int E, int N) {
  int i = blockIdx.x * 256 + threadIdx.x;
  if (i < E) {
    int s = ei[i], d = ei[E + i];
    int p = atomicAdd(&cursor[d], 1);
    csr_src[p] = s;
  } else if (i < E + N) {
    int n = i - E;
    int p = atomicAdd(&cursor[n], 1);
    csr_src[p] = n;
  }
}

// ---------------- split fp32 -> (hi, lo) bf16 ----------------
__global__ void k_split(const float* __restrict__ src, bf16* __restrict__ hi,
                        bf16* __restrict__ lo, int n) {
  int i = blockIdx.x * 256 + threadIdx.x;
  if (i < n) {
    float v = src[i];
    bf16 h = (bf16)v;
    hi[i] = h;
    lo[i] = (bf16)(v - (float)h);
  }
}

// W [256k,256n] row-major -> Wt hi/lo [n][k] bf16
__global__ void k_transpose_w(const float* __restrict__ W, bf16* __restrict__ Wth,
                              bf16* __restrict__ Wtl) {
  int k = blockIdx.x, n = threadIdx.x;
  float v = W[k * 256 + n];
  bf16 h = (bf16)v;
  Wth[n * 256 + k] = h;
  Wtl[n * 256 + k] = (bf16)(v - (float)h);
}

// concat head weights [Wmu|Wlv|Wa|pad] -> transposed split [128][256] + bias_cat[128]
__global__ void k_build_head_w(const float* __restrict__ Wmu, const float* __restrict__ bmu,
                               const float* __restrict__ Wlv, const float* __restrict__ blv,
                               const float* __restrict__ Wa, const float* __restrict__ ba,
                               bf16* __restrict__ Whh, bf16* __restrict__ Whl,
                               float* __restrict__ bias_cat) {
  int k = blockIdx.x, n = threadIdx.x;  // k 0..255, n 0..127
  float v = 0.f;
  if (n < 32) v = Wmu[k * 32 + n];
  else if (n < 64) v = Wlv[k * 32 + (n - 32)];
  else if (n < 94) v = Wa[k * 30 + (n - 64)];
  bf16 h = (bf16)v;
  Whh[n * 256 + k] = h;
  Whl[n * 256 + k] = (bf16)(v - (float)h);
  if (k == 0) {
    float b = 0.f;
    if (n < 32) b = bmu[n];
    else if (n < 64) b = blv[n - 32];
    else if (n < 94) b = ba[n - 64];
    bias_cat[n] = b;
  }
}

// ---------------- split-precision bf16 MFMA GEMM ----------------
// C[M,ldc] = A[M,256] @ Bt^T + bias. Output: fp32 Cf (with bias) OR fp16 C16 (no bias).
__global__ __launch_bounds__(256) void k_gemm(
    const bf16* __restrict__ Ah, const bf16* __restrict__ Al,
    const bf16* __restrict__ Bh, const bf16* __restrict__ Bl,
    const float* __restrict__ bias, float* __restrict__ Cf, fp16* __restrict__ C16,
    int M, int ldc) {
  __shared__ bf16 Ash[128 * 32];
  __shared__ bf16 Asl[128 * 32];
  __shared__ bf16 Bsh[128 * 32];
  __shared__ bf16 Bsl[128 * 32];
  const int t = threadIdx.x;
  const int wave = t >> 6, lane = t & 63;
  const int m0 = blockIdx.x * 128, n0 = blockIdx.y * 128;
  const int lrow = lane & 15, lq = lane >> 4;
  const int wm = (wave >> 1) * 64, wn = (wave & 1) * 64;

  f32x4 acc[4][4] = {};

  const int j0 = wave * 64 + lane, j1 = j0 + 256;
  const int ar0 = j0 >> 2, ar1 = j1 >> 2;
  const int ak0 = ((j0 & 3) ^ ((ar0 >> 1) & 3)) * 8;
  const int ak1 = ((j1 & 3) ^ ((ar1 >> 1) & 3)) * 8;
  const int gm0 = min(m0 + ar0, M - 1), gm1 = min(m0 + ar1, M - 1);
  const size_t oa0 = (size_t)gm0 * 256 + ak0, oa1 = (size_t)gm1 * 256 + ak1;
  const size_t ob0 = (size_t)(n0 + ar0) * 256 + ak0, ob1 = (size_t)(n0 + ar1) * 256 + ak1;
  const int l0 = wave * 512, l1 = 2048 + wave * 512;

  for (int k0 = 0; k0 < 256; k0 += 32) {
    __syncthreads();
    gld_lds16(Ah + oa0 + k0, Ash + l0);
    gld_lds16(Ah + oa1 + k0, Ash + l1);
    gld_lds16(Al + oa0 + k0, Asl + l0);
    gld_lds16(Al + oa1 + k0, Asl + l1);
    gld_lds16(Bh + ob0 + k0, Bsh + l0);
    gld_lds16(Bh + ob1 + k0, Bsh + l1);
    gld_lds16(Bl + ob0 + k0, Bsl + l0);
    gld_lds16(Bl + ob1 + k0, Bsl + l1);
    __syncthreads();
    bf16x8 afh[4], afl[4], bfh[4], bfl[4];
#pragma unroll
    for (int mi = 0; mi < 4; mi++) {
      int row = wm + mi * 16 + lrow;
      int off = row * 32 + ((lq ^ ((row >> 1) & 3)) << 3);
      afh[mi] = *(const bf16x8*)(Ash + off);
      afl[mi] = *(const bf16x8*)(Asl + off);
    }
#pragma unroll
    for (int ni = 0; ni < 4; ni++) {
      int row = wn + ni * 16 + lrow;
      int off = row * 32 + ((lq ^ ((row >> 1) & 3)) << 3);
      bfh[ni] = *(const bf16x8*)(Bsh + off);
      bfl[ni] = *(const bf16x8*)(Bsl + off);
    }
#pragma unroll
    for (int mi = 0; mi < 4; mi++)
#pragma unroll
      for (int ni = 0; ni < 4; ni++) {
        acc[mi][ni] = __builtin_amdgcn_mfma_f32_16x16x32_bf16(afl[mi], bfh[ni], acc[mi][ni], 0, 0, 0);
        acc[mi][ni] = __builtin_amdgcn_mfma_f32_16x16x32_bf16(afh[mi], bfl[ni], acc[mi][ni], 0, 0, 0);
        acc[mi][ni] = __builtin_amdgcn_mfma_f32_16x16x32_bf16(afh[mi], bfh[ni], acc[mi][ni], 0, 0, 0);
      }
  }

#pragma unroll
  for (int mi = 0; mi < 4; mi++) {
    const int mb = m0 + wm + mi * 16 + lq * 4;
#pragma unroll
    for (int ni = 0; ni < 4; ni++) {
      const int n = n0 + wn + ni * 16 + lrow;
#pragma unroll
      for (int r = 0; r < 4; r++) {
        int m = mb + r;
        if (m < M) {
          if (C16) C16[(size_t)m * ldc + n] = (fp16)acc[mi][ni][r];
          else     Cf[(size_t)m * ldc + n] = acc[mi][ni][r] + (bias ? bias[n] : 0.f);
        }
      }
    }
  }
}

// ---------------- per-node attention scores al_s/al_d [N,4] (fp16 h) ----------------
__global__ __launch_bounds__(256) void k_al(
    const fp16* __restrict__ h, const float* __restrict__ asrc, const float* __restrict__ adst,
    float* __restrict__ als, float* __restrict__ ald, int N) {
  const int t = threadIdx.x;
  const float as = asrc[t], ad = adst[t];
  const int head = t >> 6;
  int nend = min(blockIdx.x * 4 + 4, N);
  for (int n = blockIdx.x * 4; n < nend; ++n) {
    float hv = (float)h[(size_t)n * 256 + t];
    float vs = hv * as, vd = hv * ad;
    for (int o = 32; o > 0; o >>= 1) {
      vs += __shfl_down(vs, o, 64);
      vd += __shfl_down(vd, o, 64);
    }
    if ((t & 63) == 0) { als[n * 4 + head] = vs; ald[n * 4 + head] = vd; }
  }
}

// -------- online softmax + weighted gather: 2 nodes/wave, lane owns 8 fp16 channels ------
__global__ __launch_bounds__(256) void k_gather(
    const fp16* __restrict__ h16, const float* __restrict__ als, const float* __restrict__ ald,
    const int* __restrict__ row_start, const int* __restrict__ csr_src,
    const float* __restrict__ bias, float* __restrict__ out, int N) {
  const int wave = threadIdx.x >> 6, lane = threadIdx.x & 63;
  const int half = lane >> 5, l32 = lane & 31;
  const int n = blockIdx.x * 8 + wave * 2 + half;
  if (n >= N) return;
  const int head = l32 >> 3;
  const int c0 = l32 * 8;
  const float adh = ald[n * 4 + head];
  const int beg = row_start[n], end = row_start[n + 1];
  float m = -__builtin_inff(), s = 0.f;
  float acc[8] = {0.f, 0.f, 0.f, 0.f, 0.f, 0.f, 0.f, 0.f};
#pragma unroll 4
  for (int i = beg; i < end; ++i) {
    const int sidx = csr_src[i];
    float e = als[sidx * 4 + head] + adh;
    e = e > 0.f ? e : NEG_SLOPE * e;
    const float mnew = fmaxf(m, e);
    const float sc = __expf(m - mnew);   // first iter: exp(-inf)=0
    const float w = __expf(e - mnew);
    m = mnew;
    s = s * sc + w;
    const half8 hv = *(const half8*)(h16 + (size_t)sidx * 256 + c0);
#pragma unroll
    for (int k = 0; k < 8; ++k) acc[k] = acc[k] * sc + w * (float)hv[k];
  }
  const float inv = 1.f / (s + 1e-16f);
  float4 o1, o2;
  const float4 b1 = *(const float4*)(bias + c0);
  const float4 b2 = *(const float4*)(bias + c0 + 4);
  o1.x = acc[0] * inv + b1.x; o1.y = acc[1] * inv + b1.y;
  o1.z = acc[2] * inv + b1.z; o1.w = acc[3] * inv + b1.w;
  o2.x = acc[4] * inv + b2.x; o2.y = acc[5] * inv + b2.y;
  o2.z = acc[6] * inv + b2.z; o2.w = acc[7] * inv + b2.w;
  *(float4*)(out + (size_t)n * 256 + c0) = o1;
  *(float4*)(out + (size_t)n * 256 + c0 + 4) = o2;
}

// ---------------- batch norm ----------------
__global__ void k_zero(float* p, int n) {
  int i = blockIdx.x * 256 + threadIdx.x;
  if (i < n) p[i] = 0.f;
}

__global__ __launch_bounds__(256) void k_bn_stats(const float* __restrict__ x,
                                                  float* __restrict__ stats, int N) {
  const int t = threadIdx.x;
  int r0 = blockIdx.x * 128;
  int rend = min(r0 + 128, N);
  float s = 0.f, sq = 0.f;
  for (int r = r0; r < rend; ++r) {
    float v = x[(size_t)r * 256 + t];
    s += v; sq += v * v;
  }
  atomicAdd(&stats[t], s);
  atomicAdd(&stats[256 + t], sq);
}

// l<2: write split bf16 activation (hi/lo). l==2: encf[idx] = relu(bn) + encf[idx] (in-place add).
__global__ __launch_bounds__(256) void k_bn_apply(
    const float* __restrict__ x, const float* __restrict__ stats,
    const float* __restrict__ g, const float* __restrict__ be,
    bf16* __restrict__ act_hi, bf16* __restrict__ act_lo, float* __restrict__ encf,
    float invN, int total) {
  int idx = blockIdx.x * 256 + threadIdx.x;
  if (idx >= total) return;
  int c = idx & 255;
  float mu = stats[c] * invN;
  float var = stats[256 + c] * invN - mu * mu;
  float v = (x[idx] - mu) * rsqrtf(var + BN_EPS) * g[c] + be[c];
  v = fmaxf(v, 0.f);
  if (act_hi) {
    bf16 h = (bf16)v;
    act_hi[idx] = h;
    act_lo[idx] = (bf16)(v - (float)h);
  }
  if (encf) encf[idx] = v + encf[idx];
}

// ---------------- VAE finish: z, out = z@Wd, copy mu/lv/aux ----------------
__global__ __launch_bounds__(256) void k_finish(
    const float* __restrict__ HEAD, const float* __restrict__ eps,
    const float* __restrict__ Wd, const float* __restrict__ bd,
    float* __restrict__ o_out, float* __restrict__ o_mu, float* __restrict__ o_lv,
    float* __restrict__ o_aux, int N) {
  __shared__ float sWd[1024];
  __shared__ float sZ[8][33];
  const int t = threadIdx.x;
  for (int i = t; i < 1024; i += 256) sWd[i] = Wd[i];
  __syncthreads();
  const int r = t >> 5, j = t & 31;
  const int n = blockIdx.x * 8 + r;
  if (n < N) {
    const float* hp = HEAD + (size_t)n * 128;
    float mu = hp[j];
    float lv = hp[32 + j];
    float z = mu + eps[(size_t)n * 32 + j] * __expf(0.5f * lv);
    sZ[r][j] = z;
    o_mu[(size_t)n * 32 + j] = mu;
    o_lv[(size_t)n * 32 + j] = lv;
    if (j < 30) o_aux[(size_t)n * 30 + j] = hp[64 + j];
  }
  __syncthreads();
  if (n < N) {
    float o = bd[j];
#pragma unroll
    for (int k = 0; k < 32; ++k) o += sZ[r][k] * sWd[k * 32 + j];
    o_out[(size_t)n * 32 + j] = o;
  }
}

// ---------------- launcher ----------------
extern "C" void kernel_launch(void* const* d_in, const int* in_sizes, int n_in,
                              void* d_out, int out_size, void* d_ws, size_t ws_size,
                              hipStream_t stream) {
  const float* x   = (const float*)d_in[0];
  const int*   ei  = (const int*)d_in[1];
  const float* eps = (const float*)d_in[2];
  const float* Wg[3]   = {(const float*)d_in[3], (const float*)d_in[9],  (const float*)d_in[15]};
  const float* asrc[3] = {(const float*)d_in[4], (const float*)d_in[10], (const float*)d_in[16]};
  const float* adst[3] = {(const float*)d_in[5], (const float*)d_in[11], (const float*)d_in[17]};
  const float* bg[3]   = {(const float*)d_in[6], (const float*)d_in[12], (const float*)d_in[18]};
  const float* gam[3]  = {(const float*)d_in[7], (const float*)d_in[13], (const float*)d_in[19]};
  const float* bet[3]  = {(const float*)d_in[8], (const float*)d_in[14], (const float*)d_in[20]};
  const float* Wr  = (const float*)d_in[21];
  const float* br  = (const float*)d_in[22];
  const float* Wmu = (const float*)d_in[23];
  const float* bmu = (const float*)d_in[24];
  const float* Wlv = (const float*)d_in[25];
  const float* blv = (const float*)d_in[26];
  const float* Wd  = (const float*)d_in[27];
  const float* bd  = (const float*)d_in[28];
  const float* Wa  = (const float*)d_in[29];
  const float* ba  = (const float*)d_in[30];

  const int N = in_sizes[0] / 256;
  const int E = in_sizes[1] / 2;

  float* outp  = (float*)d_out;
  float* o_out = outp;
  float* o_mu  = outp + (size_t)N * 32;
  float* o_lv  = outp + (size_t)N * 64;
  float* o_aux = outp + (size_t)N * 96;
  float* o_enc = outp + (size_t)N * 96 + (size_t)N * 30;

  char* p = (char*)d_ws;
  auto carve = [&](size_t bytes) -> char* {
    char* r = p;
    p += (bytes + 255) & ~(size_t)255;
    return r;
  };
  int* counts    = (int*)carve((size_t)N * 4);
  int* row_start = (int*)carve(((size_t)N + 1) * 4);
  int* cursor    = (int*)carve((size_t)N * 4);
  int* csr_src   = (int*)carve((size_t)(E + N) * 4);
  int* bsums     = (int*)carve(((size_t)N / 1024 + 2) * 4);
  bf16* Wth[4];
  bf16* Wtl[4];
  for (int i = 0; i < 4; ++i) {
    Wth[i] = (bf16*)carve(256 * 256 * 2);
    Wtl[i] = (bf16*)carve(256 * 256 * 2);
  }
  bf16* Whh = (bf16*)carve(128 * 256 * 2);
  bf16* Whl = (bf16*)carve(128 * 256 * 2);
  float* bias_cat = (float*)carve(128 * 4);
  bf16* Ahi = (bf16*)carve((size_t)N * 256 * 2);
  bf16* Alo = (bf16*)carve((size_t)N * 256 * 2);
  fp16* H16 = (fp16*)carve((size_t)N * 256 * 2);   // h in fp16 for scores+gather
  float* FHEAD = (float*)carve((size_t)N * 128 * 4);  // head GEMM out
  float* AGG = (float*)carve((size_t)N * 256 * 4);
  float* als = (float*)carve((size_t)N * 4 * 4);
  float* ald = (float*)carve((size_t)N * 4 * 4);
  float* stats = (float*)carve(512 * 4);

  dim3 b256(256);

  // CSR by dst (self-loops included as count init = 1)
  const int nb_scan = (N + 1023) / 1024;
  k_init_counts<<<(N + 255) / 256, b256, 0, stream>>>(counts, N);
  k_count<<<(E + 255) / 256, b256, 0, stream>>>(ei, counts, E);
  k_scan1<<<nb_scan, b256, 0, stream>>>(counts, row_start, bsums, N);
  k_scan2<<<1, 64, 0, stream>>>(bsums, row_start, nb_scan, N);
  k_scan3<<<(N + 255) / 256, b256, 0, stream>>>(row_start, cursor, bsums, N);
  k_fill<<<(E + N + 255) / 256, b256, 0, stream>>>(ei, cursor, csr_src, E, N);

  // conversions
  k_split<<<((size_t)N * 256 + 255) / 256, b256, 0, stream>>>(x, Ahi, Alo, N * 256);
  k_transpose_w<<<256, b256, 0, stream>>>(Wr, Wth[0], Wtl[0]);
  for (int l = 0; l < 3; ++l)
    k_transpose_w<<<256, b256, 0, stream>>>(Wg[l], Wth[l + 1], Wtl[l + 1]);
  k_build_head_w<<<256, dim3(128), 0, stream>>>(Wmu, bmu, Wlv, blv, Wa, ba, Whh, Whl, bias_cat);

  dim3 ggrid((N + 127) / 128, 2);
  // residual = x @ Wr + br -> o_enc (bn3 adds relu(bn) in-place later)
  k_gemm<<<ggrid, b256, 0, stream>>>(Ahi, Alo, Wth[0], Wtl[0], br, o_enc, nullptr, N, 256);

  const float invN = 1.0f / (float)N;
  for (int l = 0; l < 3; ++l) {
    k_gemm<<<ggrid, b256, 0, stream>>>(Ahi, Alo, Wth[l + 1], Wtl[l + 1], nullptr, nullptr, H16, N, 256);
    k_al<<<(N + 3) / 4, b256, 0, stream>>>(H16, asrc[l], adst[l], als, ald, N);
    k_zero<<<2, b256, 0, stream>>>(stats, 512);
    k_gather<<<(N + 7) / 8, b256, 0, stream>>>(H16, als, ald, row_start, csr_src, bg[l], AGG, N);
    k_bn_stats<<<(N + 127) / 128, b256, 0, stream>>>(AGG, stats, N);
    if (l < 2)
      k_bn_apply<<<((size_t)N * 256 + 255) / 256, b256, 0, stream>>>(
          AGG, stats, gam[l], bet[l], Ahi, Alo, nullptr, invN, N * 256);
    else
      k_bn_apply<<<((size_t)N * 256 + 255) / 256, b256, 0, stream>>>(
          AGG, stats, gam[l], bet[l], nullptr, nullptr, o_enc, invN, N * 256);
  }

  // enc -> split bf16 for head GEMM
  k_split<<<((size_t)N * 256 + 255) / 256, b256, 0, stream>>>(o_enc, Ahi, Alo, N * 256);
  // HEAD[N,128] = enc @ [Wmu|Wlv|Wa] + bias_cat
  dim3 hgrid((N + 127) / 128, 1);
  k_gemm<<<hgrid, b256, 0, stream>>>(Ahi, Alo, Whh, Whl, bias_cat, FHEAD, nullptr, N, 128);
  k_finish<<<(N + 7) / 8, b256, 0, stream>>>(FHEAD, eps, Wd, bd, o_out, o_mu, o_lv, o_aux, N);
}